// Round 15
// baseline (199.719 us; speedup 1.0000x reference)
//
#include <hip/hip_runtime.h>
#include <hip/hip_bf16.h>
#include <math.h>

#define BATCH 4
#define N 2048
#define D 256
#define NH 4
#define DH 64
#define TOPK 9
#define NEG_BIG -1e30f

typedef __bf16 bf16;
typedef __bf16 bf16x4 __attribute__((ext_vector_type(4)));
typedef __bf16 bf16x8 __attribute__((ext_vector_type(8)));
typedef float f32x4 __attribute__((ext_vector_type(4)));

#define PK3(a,b,c) ((a) | ((b) << 2) | ((c) << 4))
#define PK6(a,b,c,d,e,f) ((a) | ((b) << 2) | ((c) << 4) | ((d) << 6) | ((e) << 8) | ((f) << 10))

// s_waitcnt with ONLY vmcnt=N. gfx9 encoding: vmcnt[3:0]@0, expcnt@4,
// lgkmcnt@8, vmcnt[5:4]@14.
#define WAITVM(Nc) __builtin_amdgcn_s_waitcnt((((Nc) & 0xf)) | (7u << 4) | (0xfu << 8) | ((((unsigned)(Nc)) >> 4) << 14))

__device__ __forceinline__ void async_cp16(const bf16* g, const bf16* l) {
  __builtin_amdgcn_global_load_lds(
      (const __attribute__((address_space(1))) void*)(uintptr_t)g,
      (__attribute__((address_space(3))) void*)(uintptr_t)l, 16, 0, 0);
}

// ---------------------------------------------------------------------------
// prep: blk<8192: x -> XsN (L2-norm, 2-way split h/m, stride 512) + norms
//       blk<9216: W{q,k,v,o} -> Wt (transpose + 2-way split)
//       else (128 blks): zero the 2 MB adjacency mask
// ---------------------------------------------------------------------------
__global__ __launch_bounds__(64) void prep_kernel(const float* __restrict__ x,
                                                  const float* __restrict__ Wq,
                                                  const float* __restrict__ Wk,
                                                  const float* __restrict__ Wv,
                                                  const float* __restrict__ Wo,
                                                  bf16* __restrict__ XsN,
                                                  bf16* __restrict__ Wt,
                                                  float* __restrict__ norms,
                                                  uint4* __restrict__ mask4) {
  int blk = blockIdx.x;
  int lane = threadIdx.x;
  if (blk < 8192) {
    float4 v = *(const float4*)(x + (size_t)blk * D + lane * 4);
    float ss = v.x * v.x + v.y * v.y + v.z * v.z + v.w * v.w;
    for (int off = 32; off; off >>= 1) ss += __shfl_down(ss, off);
    ss = __shfl(ss, 0);
    float nrm = fmaxf(sqrtf(ss), 1e-12f);
    if (lane == 0) norms[blk] = nrm;
    float sc = 1.0f / nrm;
    float xs[4] = {v.x * sc, v.y * sc, v.z * sc, v.w * sc};
    bf16* o = XsN + (size_t)blk * 512 + lane * 4;
#pragma unroll
    for (int j = 0; j < 4; ++j) {
      float xv = xs[j];
      bf16 h = (bf16)xv;
      o[j] = h;
      o[256 + j] = (bf16)(xv - (float)h);
    }
  } else if (blk < 9216) {
    int jj = blk - 8192;
    const float* W = (jj < 256) ? Wq : (jj < 512) ? Wk : (jj < 768) ? Wv : Wo;
    int j = jj & 255;
    bf16* dst = Wt + (size_t)jj * 512;
    for (int k = lane; k < 256; k += 64) {
      float w = W[(size_t)k * D + j];
      bf16 h = (bf16)w;
      dst[k] = h;
      dst[256 + k] = (bf16)(w - (float)h);
    }
  } else {
    int base = (blk - 9216) * 1024 + lane;
#pragma unroll
    for (int t = 0; t < 16; ++t)
      mask4[base + t * 64] = make_uint4(0, 0, 0, 0);
  }
}

// ---------------------------------------------------------------------------
// GEMM core — BK=64, LDS dbuf, global_load_lds, raw s_barrier + vmcnt(8),
// XOR swizzle key (row&7) (0 conflicts, rounds 7-8).
// outmode 1: fp32 nontemporal + optional mirror (sim).
// outmode 2: bf16 with per-row norm rescale (qkv).
// ---------------------------------------------------------------------------
__device__ __forceinline__ void gemm_core(bf16* As, bf16* Bs,
                                          const bf16* __restrict__ Ab,
                                          const bf16* __restrict__ Bb,
                                          void* __restrict__ Cvoid,
                                          int lda, int ldb, int ldc,
                                          int nsteps, int amap, int bmap,
                                          int row0, int col0,
                                          int outmode, bool mirror,
                                          const float* __restrict__ rowscale) {
  int tid = threadIdx.x;
  int lane = tid & 63;
  int wv = tid >> 6;
  int wm = (wv >> 1) * 64;
  int wn = (wv & 1) * 64;

  int rbase = tid >> 3;
  int gperm = (tid & 7) ^ (rbase & 7);
  const bf16* ga0 = Ab + (size_t)rbase * lda + gperm * 8;
  const bf16* gb0 = Bb + (size_t)rbase * ldb + gperm * 8;
  int ldsoff = tid * 8;  // 16 B per thread

  int fr = lane & 15;
  int fq = (lane >> 4) * 8;

  f32x4 acc[4][4] = {};

  auto issue = [&](int st, int buf) {
    int ch = st >> 2;
    int aoff = (((amap >> (ch * 2)) & 3) << 8) | ((st & 3) << 6);
    int boff = (((bmap >> (ch * 2)) & 3) << 8) | ((st & 3) << 6);
#pragma unroll
    for (int q = 0; q < 4; ++q)
      async_cp16(ga0 + (size_t)q * 32 * lda + aoff, &As[buf * 8192 + ldsoff + q * 2048]);
#pragma unroll
    for (int q = 0; q < 4; ++q)
      async_cp16(gb0 + (size_t)q * 32 * ldb + boff, &Bs[buf * 8192 + ldsoff + q * 2048]);
  };

  issue(0, 0);
  for (int st = 0; st < nsteps; ++st) {
    int buf = st & 1;
    if (st + 1 < nsteps) {
      issue(st + 1, buf ^ 1);
      WAITVM(8);
    } else {
      WAITVM(0);
    }
    __builtin_amdgcn_s_barrier();
#pragma unroll
    for (int ks = 0; ks < 64; ks += 32) {
      bf16x8 af[4], bfr[4];
#pragma unroll
      for (int mi = 0; mi < 4; ++mi) {
        int r = wm + mi * 16 + fr;
        int G = (ks + fq) >> 3;
        af[mi] = *(const bf16x8*)&As[buf * 8192 + r * 64 + ((G ^ (r & 7)) << 3)];
      }
#pragma unroll
      for (int nj = 0; nj < 4; ++nj) {
        int r = wn + nj * 16 + fr;
        int G = (ks + fq) >> 3;
        bfr[nj] = *(const bf16x8*)&Bs[buf * 8192 + r * 64 + ((G ^ (r & 7)) << 3)];
      }
#pragma unroll
      for (int mi = 0; mi < 4; ++mi)
#pragma unroll
        for (int nj = 0; nj < 4; ++nj)
          acc[mi][nj] = __builtin_amdgcn_mfma_f32_16x16x32_bf16(af[mi], bfr[nj], acc[mi][nj], 0, 0, 0);
    }
    __builtin_amdgcn_s_barrier();
  }

  int er = (lane >> 4) * 4;
  int ec = lane & 15;
#pragma unroll
  for (int mi = 0; mi < 4; ++mi) {
    int rb = row0 + wm + mi * 16 + er;
    float scl[4] = {1.f, 1.f, 1.f, 1.f};
    if (rowscale) {
      float4 s4 = *(const float4*)(rowscale + rb);
      scl[0] = s4.x; scl[1] = s4.y; scl[2] = s4.z; scl[3] = s4.w;
    }
#pragma unroll
    for (int nj = 0; nj < 4; ++nj) {
      int cb = col0 + wn + nj * 16 + ec;
      if (outmode == 1) {
        float* Cb = (float*)Cvoid;
#pragma unroll
        for (int reg = 0; reg < 4; ++reg)
          __builtin_nontemporal_store(acc[mi][nj][reg],
                                      &Cb[(size_t)(rb + reg) * ldc + cb]);
        if (mirror) {
#pragma unroll
          for (int reg = 0; reg < 4; ++reg)
            __builtin_nontemporal_store(acc[mi][nj][reg],
                                        &Cb[(size_t)cb * ldc + rb + reg]);
        }
      } else {
        bf16* Cb = (bf16*)Cvoid;
#pragma unroll
        for (int reg = 0; reg < 4; ++reg)
          Cb[(size_t)(rb + reg) * ldc + cb] = (bf16)(acc[mi][nj][reg] * scl[reg]);
      }
    }
  }
}

// sim-only dispatch (small-ws fallback): grid (544)
__global__ __launch_bounds__(256) void gemm_sim_kernel(const bf16* __restrict__ XsN,
                                                       float* __restrict__ sim,
                                                       int amap, int bmap) {
  __shared__ bf16 As[2 * 128 * 64];
  __shared__ bf16 Bs[2 * 128 * 64];
  int g = blockIdx.x;
  int xcd = g & 7;
  int slot = g >> 3;
  int z = xcd >> 1;
  int t = (xcd & 1) * 68 + slot;
  int by = 0;
  while (t >= 16 - by) { t -= 16 - by; ++by; }
  int bx = by + t;
  gemm_core(As, Bs,
            XsN + (size_t)z * N * 512 + (size_t)by * 128 * 512,
            XsN + (size_t)z * N * 512 + (size_t)bx * 128 * 512,
            sim + (size_t)z * N * N,
            512, 512, N, 12, amap, bmap, by * 128, bx * 128,
            1, bx != by, nullptr);
}

// generic qkv dispatch (small-ws fallback): grid (6, 64), bf16 out
__global__ __launch_bounds__(256) void gemm_qkv_kernel(const bf16* __restrict__ XsN,
                                                       const bf16* __restrict__ Wt,
                                                       bf16* __restrict__ qkv,
                                                       int amap, int bmap,
                                                       const float* __restrict__ norms) {
  __shared__ bf16 As[2 * 128 * 64];
  __shared__ bf16 Bs[2 * 128 * 64];
  gemm_core(As, Bs,
            XsN + (size_t)blockIdx.y * 128 * 512,
            Wt + (size_t)blockIdx.x * 128 * 512,
            qkv, 512, 512, 768, 8, amap, bmap,
            blockIdx.y * 128, blockIdx.x * 128, 2, false, norms);
}

// fused sim + qkv dispatch (big-ws path): grid (928)
__global__ __launch_bounds__(256) void gemm_fused_kernel(const bf16* __restrict__ XsN,
                                                         float* __restrict__ sim,
                                                         int amap_s, int bmap_s,
                                                         const bf16* __restrict__ Wt,
                                                         bf16* __restrict__ qkv,
                                                         int amap_q, int bmap_q,
                                                         const float* __restrict__ norms) {
  __shared__ bf16 As[2 * 128 * 64];
  __shared__ bf16 Bs[2 * 128 * 64];
  int g = blockIdx.x;
  if (g < 544) {
    int xcd = g & 7;
    int slot = g >> 3;
    int z = xcd >> 1;
    int t = (xcd & 1) * 68 + slot;
    int by = 0;
    while (t >= 16 - by) { t -= 16 - by; ++by; }
    int bx = by + t;
    gemm_core(As, Bs,
              XsN + (size_t)z * N * 512 + (size_t)by * 128 * 512,
              XsN + (size_t)z * N * 512 + (size_t)bx * 128 * 512,
              sim + (size_t)z * N * N,
              512, 512, N, 12, amap_s, bmap_s, by * 128, bx * 128,
              1, bx != by, nullptr);
  } else {
    int t = g - 544;
    int bx = t % 6;
    int by = t / 6;
    gemm_core(As, Bs,
              XsN + (size_t)by * 128 * 512,
              Wt + (size_t)bx * 128 * 512,
              qkv, 512, 512, 768, 8, amap_q, bmap_q,
              by * 128, bx * 128, 2, false, norms);
  }
}

// ---------------------------------------------------------------------------
// top-9 per row by 9x extract-max, fused adjacency write.  One wave per row;
// mask pre-zeroed.  Selection set identical to lax.top_k.
// ---------------------------------------------------------------------------
__global__ __launch_bounds__(64) void topk_adj_kernel(const float* __restrict__ sim,
                                                      unsigned* __restrict__ mask) {
  int row = blockIdx.x;
  int lane = threadIdx.x;
  int b = row >> 11, r = row & 2047;
  const float* srow = sim + (size_t)row * N;
  float v[32];
#pragma unroll
  for (int it = 0; it < 8; ++it) {
    float4 q = *(const float4*)(srow + it * 256 + lane * 4);
    v[it * 4 + 0] = q.x; v[it * 4 + 1] = q.y;
    v[it * 4 + 2] = q.z; v[it * 4 + 3] = q.w;
  }
  unsigned removed = 0;
  for (int rs = 0; rs < TOPK; ++rs) {
    float m = -3e38f;
    int mi = 0;
#pragma unroll
    for (int i = 0; i < 32; ++i) {
      float vv = ((removed >> i) & 1u) ? -3e38f : v[i];
      if (vv > m) { m = vv; mi = i; }
    }
    int gidx = ((mi >> 2) << 8) + lane * 4 + (mi & 3);
    for (int off = 32; off; off >>= 1) {
      float om = __shfl_down(m, off);
      int og = __shfl_down(gidx, off);
      if (om > m || (om == m && og < gidx)) { m = om; gidx = og; }
    }
    gidx = __shfl(gidx, 0);
    if (((gidx >> 2) & 63) == lane)
      removed |= 1u << (((gidx >> 8) << 2) | (gidx & 3));
    if (lane == 0) {
      atomicOr(&mask[(size_t)row * 64 + (gidx >> 5)], 1u << (gidx & 31));
      atomicOr(&mask[(((size_t)b << 11) + gidx) * 64 + (r >> 5)], 1u << (r & 31));
    }
  }
}

// ---------------------------------------------------------------------------
// sparse attention: 4 waves/block, one (b,n) row per wave; XCD-aware decode;
// qkv is bf16 [8192][768]; writes bf16-split aos (stride 512).
// ---------------------------------------------------------------------------
__global__ __launch_bounds__(256) void attn_kernel(const bf16* __restrict__ qkv,
                                                   const unsigned* __restrict__ mask,
                                                   bf16* __restrict__ aos) {
  __shared__ float sq[4][256];
  __shared__ unsigned short nbr[4][2048];
  __shared__ int s_nn[4];
  int wv = threadIdx.x >> 6;
  int lane = threadIdx.x & 63;
  int g = blockIdx.x;
  int xcd = g & 7;
  int b = xcd >> 1;
  int tile = (xcd & 1) * 256 + (g >> 3);
  int bn = b * N + tile * 4 + wv;
  if (lane == 0) s_nn[wv] = 0;
  {
    bf16x4 qv = *(const bf16x4*)(qkv + (size_t)bn * 768 + lane * 4);
#pragma unroll
    for (int j = 0; j < 4; ++j) sq[wv][lane * 4 + j] = (float)qv[j];
  }
  __syncthreads();
  unsigned bits = mask[(size_t)bn * (N / 32) + lane];
  while (bits) {
    int bit = __ffs(bits) - 1;
    bits &= bits - 1;
    int p = atomicAdd(&s_nn[wv], 1);
    nbr[wv][p] = (unsigned short)(lane * 32 + bit);
  }
  __syncthreads();
  int nn = s_nn[wv];
  const bf16* base = qkv + (size_t)b * N * 768;
  float acc[4] = {0.f, 0.f, 0.f, 0.f};

  auto score4 = [&](int j, float* s) {
    const bf16* kr = base + (size_t)j * 768 + 256;
#pragma unroll
    for (int h = 0; h < 4; ++h) {
      float a = 0.f;
#pragma unroll
      for (int c = 0; c < DH; c += 8) {
        bf16x8 kk = *(const bf16x8*)(kr + h * DH + c);
#pragma unroll
        for (int t = 0; t < 8; ++t) a += sq[wv][h * DH + c + t] * (float)kk[t];
      }
      s[h] = a * 0.125f;
    }
  };

  if (nn <= 64) {
    float s[4] = {NEG_BIG, NEG_BIG, NEG_BIG, NEG_BIG};
    if (lane < nn) score4(nbr[wv][lane], s);
    float w[4], l[4];
#pragma unroll
    for (int h = 0; h < 4; ++h) {
      float m = s[h];
      for (int off = 32; off; off >>= 1) m = fmaxf(m, __shfl_down(m, off));
      m = __shfl(m, 0);
      float e = (lane < nn) ? __expf(s[h] - m) : 0.f;
      float ls = e;
      for (int off = 32; off; off >>= 1) ls += __shfl_down(ls, off);
      l[h] = __shfl(ls, 0);
      w[h] = e;
    }
    int i = 0;
    for (; i + 4 <= nn; i += 4) {
      int j0 = nbr[wv][i + 0], j1 = nbr[wv][i + 1];
      int j2 = nbr[wv][i + 2], j3 = nbr[wv][i + 3];
      const bf16* p0 = base + (size_t)j0 * 768 + 512;
      const bf16* p1 = base + (size_t)j1 * 768 + 512;
      const bf16* p2 = base + (size_t)j2 * 768 + 512;
      const bf16* p3 = base + (size_t)j3 * 768 + 512;
#pragma unroll
      for (int h = 0; h < 4; ++h) {
        acc[h] += __shfl(w[h], i + 0) * (float)p0[h * DH + lane] +
                  __shfl(w[h], i + 1) * (float)p1[h * DH + lane] +
                  __shfl(w[h], i + 2) * (float)p2[h * DH + lane] +
                  __shfl(w[h], i + 3) * (float)p3[h * DH + lane];
      }
    }
    for (; i < nn; ++i) {
      const bf16* p0 = base + (size_t)nbr[wv][i] * 768 + 512;
#pragma unroll
      for (int h = 0; h < 4; ++h) acc[h] += __shfl(w[h], i) * (float)p0[h * DH + lane];
    }
#pragma unroll
    for (int h = 0; h < 4; ++h) acc[h] /= l[h];
  } else {
    float m[4] = {NEG_BIG, NEG_BIG, NEG_BIG, NEG_BIG};
    for (int i0 = 0; i0 < nn; i0 += 64) {
      float s[4] = {NEG_BIG, NEG_BIG, NEG_BIG, NEG_BIG};
      if (i0 + lane < nn) score4(nbr[wv][i0 + lane], s);
#pragma unroll
      for (int h = 0; h < 4; ++h) m[h] = fmaxf(m[h], s[h]);
    }
#pragma unroll
    for (int h = 0; h < 4; ++h) {
      for (int off = 32; off; off >>= 1) m[h] = fmaxf(m[h], __shfl_down(m[h], off));
      m[h] = __shfl(m[h], 0);
    }
    float l[4] = {0.f, 0.f, 0.f, 0.f};
    for (int i0 = 0; i0 < nn; i0 += 64) {
      float s[4] = {NEG_BIG, NEG_BIG, NEG_BIG, NEG_BIG};
      if (i0 + lane < nn) score4(nbr[wv][i0 + lane], s);
      float e[4];
#pragma unroll
      for (int h = 0; h < 4; ++h) {
        e[h] = (i0 + lane < nn) ? __expf(s[h] - m[h]) : 0.f;
        float ls = e[h];
        for (int off = 32; off; off >>= 1) ls += __shfl_down(ls, off);
        l[h] += __shfl(ls, 0);
      }
      int lim = min(64, nn - i0);
      for (int ii = 0; ii < lim; ++ii) {
        const bf16* p0 = base + (size_t)nbr[wv][i0 + ii] * 768 + 512;
#pragma unroll
        for (int h = 0; h < 4; ++h) acc[h] += __shfl(e[h], ii) * (float)p0[h * DH + lane];
      }
    }
#pragma unroll
    for (int h = 0; h < 4; ++h) acc[h] /= l[h];
  }
#pragma unroll
  for (int h = 0; h < 4; ++h) {
    float a = acc[h];
    bf16 hi = (bf16)a;
    aos[(size_t)bn * 512 + h * DH + lane] = hi;
    aos[(size_t)bn * 512 + 256 + h * DH + lane] = (bf16)(a - (float)hi);
  }
}

// ---------------------------------------------------------------------------
// fused out-projection + bias + residual + LayerNorm -> out.
// 128 rows x 256 cols per block (grid 64), BK=32, 3-buffer... dbuf, swizzle
// key (r>>1)&3 (0 conflicts, round 10).  Per-row LN: 16-lane shuffle +
// 2-col-wave LDS reduction.
// ---------------------------------------------------------------------------
__global__ __launch_bounds__(256) void projln_kernel(const bf16* __restrict__ A,
                                                     const bf16* __restrict__ Bw,
                                                     const float* __restrict__ x,
                                                     const float* __restrict__ bo,
                                                     const float* __restrict__ gamma,
                                                     const float* __restrict__ beta,
                                                     float* __restrict__ out) {
  __shared__ bf16 As[2 * 128 * 32];
  __shared__ bf16 Bs[2 * 256 * 32];
  __shared__ float rsum[128][2];
  __shared__ float rsq[128][2];
  int tid = threadIdx.x;
  int lane = tid & 63;
  int wv = tid >> 6;
  int wm = (wv >> 1) * 64;
  int wn = (wv & 1) * 128;
  int row0 = blockIdx.x * 128;

  int rt = tid >> 2;
  int gperm = (tid & 3) ^ ((rt >> 1) & 3);
  const bf16* ga0 = A + (size_t)(row0 + rt) * 512 + gperm * 8;
  const bf16* gb0 = Bw + (size_t)rt * 512 + gperm * 8;

  int fr = lane & 15;
  int G = lane >> 4;

  f32x4 acc[4][8] = {};

  auto issue = [&](int st, int buf) {
    int aoff = ((st >> 3) << 8) | ((st & 7) << 5);  // A: ch0 h, ch1 m
    int boff = (st & 7) << 5;                       // B: h only
#pragma unroll
    for (int q = 0; q < 2; ++q)
      async_cp16(ga0 + (size_t)q * 64 * 512 + aoff, &As[buf * 4096 + tid * 8 + q * 2048]);
#pragma unroll
    for (int q = 0; q < 4; ++q)
      async_cp16(gb0 + (size_t)q * 64 * 512 + boff, &Bs[buf * 8192 + tid * 8 + q * 2048]);
  };

  issue(0, 0);
  for (int st = 0; st < 16; ++st) {
    int buf = st & 1;
    if (st + 1 < 16) {
      issue(st + 1, buf ^ 1);
      WAITVM(6);
    } else {
      WAITVM(0);
    }
    __builtin_amdgcn_s_barrier();
    bf16x8 af[4], bfr[8];
#pragma unroll
    for (int mi = 0; mi < 4; ++mi) {
      int r = wm + mi * 16 + fr;
      af[mi] = *(const bf16x8*)&As[buf * 4096 + r * 32 + ((G ^ ((r >> 1) & 3)) << 3)];
    }
#pragma unroll
    for (int nj = 0; nj < 8; ++nj) {
      int r = wn + nj * 16 + fr;
      bfr[nj] = *(const bf16x8*)&Bs[buf * 8192 + r * 32 + ((G ^ ((r >> 1) & 3)) << 3)];
    }
#pragma unroll
    for (int mi = 0; mi < 4; ++mi)
#pragma unroll
      for (int nj = 0; nj < 8; ++nj)
        acc[mi][nj] = __builtin_amdgcn_mfma_f32_16x16x32_bf16(af[mi], bfr[nj], acc[mi][nj], 0, 0, 0);
    __builtin_amdgcn_s_barrier();
  }

  int er = (lane >> 4) * 4;
  int ec = lane & 15;
  float bo_c[8], ga_c[8], be_c[8];
#pragma unroll
  for (int nj = 0; nj < 8; ++nj) {
    int c = wn + nj * 16 + ec;
    bo_c[nj] = bo[c]; ga_c[nj] = gamma[c]; be_c[nj] = beta[c];
  }
#pragma unroll
  for (int mi = 0; mi < 4; ++mi)
#pragma unroll
    for (int reg = 0; reg < 4; ++reg) {
      int rloc = wm + mi * 16 + er + reg;
      const float* xr = x + (size_t)(row0 + rloc) * D;
      float su = 0.f, s2 = 0.f;
#pragma unroll
      for (int nj = 0; nj < 8; ++nj) {
        float u = acc[mi][nj][reg] + bo_c[nj] + xr[wn + nj * 16 + ec];
        su += u; s2 += u * u;
      }
#pragma unroll
      for (int m = 1; m <= 8; m <<= 1) {
        su += __shfl_xor(su, m);
        s2 += __shfl_xor(s2, m);
      }
      if (ec == 0) { rsum[rloc][wv & 1] = su; rsq[rloc][wv & 1] = s2; }
    }
  __syncthreads();
#pragma unroll
  for (int mi = 0; mi < 4; ++mi)
#pragma unroll
    for (int reg = 0; reg < 4; ++reg) {
      int rloc = wm + mi * 16 + er + reg;
      float s = rsum[rloc][0] + rsum[rloc][1];
      float q2 = rsq[rloc][0] + rsq[rloc][1];
      float mean = s * (1.0f / D);
      float var = q2 * (1.0f / D) - mean * mean;
      float rstd = rsqrtf(var + 1e-5f);
      const float* xr = x + (size_t)(row0 + rloc) * D;
      float* orow = out + (size_t)(row0 + rloc) * D;
#pragma unroll
      for (int nj = 0; nj < 8; ++nj) {
        float u = acc[mi][nj][reg] + bo_c[nj] + xr[wn + nj * 16 + ec];
        orow[wn + nj * 16 + ec] = (u - mean) * rstd * ga_c[nj] + be_c[nj];
      }
    }
}

// ---------------------------------------------------------------------------
// Workspace.  Common: XsN [0,8.39M) | sim [12.58M,79.69M) | norms@79.69M
//                     mask@79.99M | Wt@82.08M (ends 83,132,416)
// BIG (ws >= 125 MB; fill shows 256 MiB): qkv(bf16)@83.13M | aos@95.72M
// SMALL: qkv@12.58M, aos@37.75M (dead-sim region, written after topk)
// ---------------------------------------------------------------------------
extern "C" void kernel_launch(void* const* d_in, const int* in_sizes, int n_in,
                              void* d_out, int out_size, void* d_ws, size_t ws_size,
                              hipStream_t stream) {
  const float* x     = (const float*)d_in[0];
  const float* Wq    = (const float*)d_in[1];
  const float* Wk    = (const float*)d_in[2];
  const float* Wv    = (const float*)d_in[3];
  const float* Wo    = (const float*)d_in[4];
  const float* bo    = (const float*)d_in[5];
  const float* gamma = (const float*)d_in[6];
  const float* beta  = (const float*)d_in[7];
  float* out = (float*)d_out;

  char* ws = (char*)d_ws;
  bf16* XsN      = (bf16*)(ws);
  float* sim     = (float*)(ws + 12582912);
  float* norms   = (float*)(ws + 79691776);
  unsigned* mask = (unsigned*)(ws + 79986688);
  bf16* Wt       = (bf16*)(ws + 82083840);

  bool big = ws_size >= (size_t)125000000;
  bf16* qkv = (bf16*)(ws + (big ? 83132416 : 12582912));
  bf16* aos = (bf16*)(ws + (big ? 95715328 : 37748736));

  const int AMAP_SIM = PK6(0, 0, 1, 0, 0, 0);  // hh + hm + mh
  const int BMAP_SIM = PK6(0, 1, 0, 0, 0, 0);
  const int AMAP_2T  = PK3(0, 1, 0);           // (h+m)_A · h_B
  const int BMAP_2T  = PK3(0, 0, 1);

  prep_kernel<<<9344, 64, 0, stream>>>(x, Wq, Wk, Wv, Wo, XsN, Wt, norms,
                                       (uint4*)mask);

  if (big) {
    gemm_fused_kernel<<<928, 256, 0, stream>>>(
        XsN, sim, AMAP_SIM, BMAP_SIM, Wt, qkv, AMAP_2T, BMAP_2T, norms);
    topk_adj_kernel<<<BATCH * N, 64, 0, stream>>>(sim, mask);
  } else {
    gemm_sim_kernel<<<544, 256, 0, stream>>>(XsN, sim, AMAP_SIM, BMAP_SIM);
    topk_adj_kernel<<<BATCH * N, 64, 0, stream>>>(sim, mask);
    gemm_qkv_kernel<<<dim3(6, 64), 256, 0, stream>>>(XsN, Wt, qkv,
                                                     AMAP_2T, BMAP_2T, norms);
  }

  attn_kernel<<<(BATCH * N) / 4, 256, 0, stream>>>(qkv, mask, aos);

  projln_kernel<<<64, 256, 0, stream>>>(aos, Wt + (size_t)768 * 512,
                                        x, bo, gamma, beta, out);
}

// Round 16
// 185.212 us; speedup vs baseline: 1.0783x; 1.0783x over previous
//
#include <hip/hip_runtime.h>
#include <hip/hip_bf16.h>
#include <math.h>

#define BATCH 4
#define N 2048
#define D 256
#define NH 4
#define DH 64
#define TOPK 9
#define NEG_BIG -1e30f

typedef __bf16 bf16;
typedef __bf16 bf16x4 __attribute__((ext_vector_type(4)));
typedef __bf16 bf16x8 __attribute__((ext_vector_type(8)));
typedef float f32x4 __attribute__((ext_vector_type(4)));

#define PK3(a,b,c) ((a) | ((b) << 2) | ((c) << 4))
#define PK6(a,b,c,d,e,f) ((a) | ((b) << 2) | ((c) << 4) | ((d) << 6) | ((e) << 8) | ((f) << 10))

// s_waitcnt with ONLY vmcnt=N. gfx9 encoding: vmcnt[3:0]@0, expcnt@4,
// lgkmcnt@8, vmcnt[5:4]@14.
#define WAITVM(Nc) __builtin_amdgcn_s_waitcnt((((Nc) & 0xf)) | (7u << 4) | (0xfu << 8) | ((((unsigned)(Nc)) >> 4) << 14))

__device__ __forceinline__ void async_cp16(const bf16* g, const bf16* l) {
  __builtin_amdgcn_global_load_lds(
      (const __attribute__((address_space(1))) void*)(uintptr_t)g,
      (__attribute__((address_space(3))) void*)(uintptr_t)l, 16, 0, 0);
}

// ---------------------------------------------------------------------------
// prep: blk<8192: x -> XsN (L2-norm, 2-way split h/m, stride 512) + norms
//       blk<9216: W{q,k,v,o} -> Wt (transpose + 2-way split)
//       else (128 blks): zero the 2 MB adjacency mask
// ---------------------------------------------------------------------------
__global__ __launch_bounds__(64) void prep_kernel(const float* __restrict__ x,
                                                  const float* __restrict__ Wq,
                                                  const float* __restrict__ Wk,
                                                  const float* __restrict__ Wv,
                                                  const float* __restrict__ Wo,
                                                  bf16* __restrict__ XsN,
                                                  bf16* __restrict__ Wt,
                                                  float* __restrict__ norms,
                                                  uint4* __restrict__ mask4) {
  int blk = blockIdx.x;
  int lane = threadIdx.x;
  if (blk < 8192) {
    float4 v = *(const float4*)(x + (size_t)blk * D + lane * 4);
    float ss = v.x * v.x + v.y * v.y + v.z * v.z + v.w * v.w;
    for (int off = 32; off; off >>= 1) ss += __shfl_down(ss, off);
    ss = __shfl(ss, 0);
    float nrm = fmaxf(sqrtf(ss), 1e-12f);
    if (lane == 0) norms[blk] = nrm;
    float sc = 1.0f / nrm;
    float xs[4] = {v.x * sc, v.y * sc, v.z * sc, v.w * sc};
    bf16* o = XsN + (size_t)blk * 512 + lane * 4;
#pragma unroll
    for (int j = 0; j < 4; ++j) {
      float xv = xs[j];
      bf16 h = (bf16)xv;
      o[j] = h;
      o[256 + j] = (bf16)(xv - (float)h);
    }
  } else if (blk < 9216) {
    int jj = blk - 8192;
    const float* W = (jj < 256) ? Wq : (jj < 512) ? Wk : (jj < 768) ? Wv : Wo;
    int j = jj & 255;
    bf16* dst = Wt + (size_t)jj * 512;
    for (int k = lane; k < 256; k += 64) {
      float w = W[(size_t)k * D + j];
      bf16 h = (bf16)w;
      dst[k] = h;
      dst[256 + k] = (bf16)(w - (float)h);
    }
  } else {
    int base = (blk - 9216) * 1024 + lane;
#pragma unroll
    for (int t = 0; t < 16; ++t)
      mask4[base + t * 64] = make_uint4(0, 0, 0, 0);
  }
}

// ---------------------------------------------------------------------------
// GEMM core — BK=64, LDS dbuf, global_load_lds, raw s_barrier + vmcnt(8),
// XOR swizzle key (row&7) (0 conflicts, rounds 7-8).
// outmode 1: fp32 nontemporal + optional mirror (sim).
// outmode 2: bf16 with per-row norm rescale (qkv).
// ---------------------------------------------------------------------------
__device__ __forceinline__ void gemm_core(bf16* As, bf16* Bs,
                                          const bf16* __restrict__ Ab,
                                          const bf16* __restrict__ Bb,
                                          void* __restrict__ Cvoid,
                                          int lda, int ldb, int ldc,
                                          int nsteps, int amap, int bmap,
                                          int row0, int col0,
                                          int outmode, bool mirror,
                                          const float* __restrict__ rowscale) {
  int tid = threadIdx.x;
  int lane = tid & 63;
  int wv = tid >> 6;
  int wm = (wv >> 1) * 64;
  int wn = (wv & 1) * 64;

  int rbase = tid >> 3;
  int gperm = (tid & 7) ^ (rbase & 7);
  const bf16* ga0 = Ab + (size_t)rbase * lda + gperm * 8;
  const bf16* gb0 = Bb + (size_t)rbase * ldb + gperm * 8;
  int ldsoff = tid * 8;  // 16 B per thread

  int fr = lane & 15;
  int fq = (lane >> 4) * 8;

  f32x4 acc[4][4] = {};

  auto issue = [&](int st, int buf) {
    int ch = st >> 2;
    int aoff = (((amap >> (ch * 2)) & 3) << 8) | ((st & 3) << 6);
    int boff = (((bmap >> (ch * 2)) & 3) << 8) | ((st & 3) << 6);
#pragma unroll
    for (int q = 0; q < 4; ++q)
      async_cp16(ga0 + (size_t)q * 32 * lda + aoff, &As[buf * 8192 + ldsoff + q * 2048]);
#pragma unroll
    for (int q = 0; q < 4; ++q)
      async_cp16(gb0 + (size_t)q * 32 * ldb + boff, &Bs[buf * 8192 + ldsoff + q * 2048]);
  };

  issue(0, 0);
  for (int st = 0; st < nsteps; ++st) {
    int buf = st & 1;
    if (st + 1 < nsteps) {
      issue(st + 1, buf ^ 1);
      WAITVM(8);
    } else {
      WAITVM(0);
    }
    __builtin_amdgcn_s_barrier();
#pragma unroll
    for (int ks = 0; ks < 64; ks += 32) {
      bf16x8 af[4], bfr[4];
#pragma unroll
      for (int mi = 0; mi < 4; ++mi) {
        int r = wm + mi * 16 + fr;
        int G = (ks + fq) >> 3;
        af[mi] = *(const bf16x8*)&As[buf * 8192 + r * 64 + ((G ^ (r & 7)) << 3)];
      }
#pragma unroll
      for (int nj = 0; nj < 4; ++nj) {
        int r = wn + nj * 16 + fr;
        int G = (ks + fq) >> 3;
        bfr[nj] = *(const bf16x8*)&Bs[buf * 8192 + r * 64 + ((G ^ (r & 7)) << 3)];
      }
#pragma unroll
      for (int mi = 0; mi < 4; ++mi)
#pragma unroll
        for (int nj = 0; nj < 4; ++nj)
          acc[mi][nj] = __builtin_amdgcn_mfma_f32_16x16x32_bf16(af[mi], bfr[nj], acc[mi][nj], 0, 0, 0);
    }
    __builtin_amdgcn_s_barrier();
  }

  int er = (lane >> 4) * 4;
  int ec = lane & 15;
#pragma unroll
  for (int mi = 0; mi < 4; ++mi) {
    int rb = row0 + wm + mi * 16 + er;
    float scl[4] = {1.f, 1.f, 1.f, 1.f};
    if (rowscale) {
      float4 s4 = *(const float4*)(rowscale + rb);
      scl[0] = s4.x; scl[1] = s4.y; scl[2] = s4.z; scl[3] = s4.w;
    }
#pragma unroll
    for (int nj = 0; nj < 4; ++nj) {
      int cb = col0 + wn + nj * 16 + ec;
      if (outmode == 1) {
        float* Cb = (float*)Cvoid;
#pragma unroll
        for (int reg = 0; reg < 4; ++reg)
          __builtin_nontemporal_store(acc[mi][nj][reg],
                                      &Cb[(size_t)(rb + reg) * ldc + cb]);
        if (mirror) {
#pragma unroll
          for (int reg = 0; reg < 4; ++reg)
            __builtin_nontemporal_store(acc[mi][nj][reg],
                                        &Cb[(size_t)cb * ldc + rb + reg]);
        }
      } else {
        bf16* Cb = (bf16*)Cvoid;
#pragma unroll
        for (int reg = 0; reg < 4; ++reg)
          Cb[(size_t)(rb + reg) * ldc + cb] = (bf16)(acc[mi][nj][reg] * scl[reg]);
      }
    }
  }
}

// sim-only dispatch (small-ws fallback): grid (544)
__global__ __launch_bounds__(256) void gemm_sim_kernel(const bf16* __restrict__ XsN,
                                                       float* __restrict__ sim,
                                                       int amap, int bmap) {
  __shared__ bf16 As[2 * 128 * 64];
  __shared__ bf16 Bs[2 * 128 * 64];
  int g = blockIdx.x;
  int xcd = g & 7;
  int slot = g >> 3;
  int z = xcd >> 1;
  int t = (xcd & 1) * 68 + slot;
  int by = 0;
  while (t >= 16 - by) { t -= 16 - by; ++by; }
  int bx = by + t;
  gemm_core(As, Bs,
            XsN + (size_t)z * N * 512 + (size_t)by * 128 * 512,
            XsN + (size_t)z * N * 512 + (size_t)bx * 128 * 512,
            sim + (size_t)z * N * N,
            512, 512, N, 12, amap, bmap, by * 128, bx * 128,
            1, bx != by, nullptr);
}

// generic qkv dispatch (small-ws fallback): grid (6, 64), bf16 out
__global__ __launch_bounds__(256) void gemm_qkv_kernel(const bf16* __restrict__ XsN,
                                                       const bf16* __restrict__ Wt,
                                                       bf16* __restrict__ qkv,
                                                       int amap, int bmap,
                                                       const float* __restrict__ norms) {
  __shared__ bf16 As[2 * 128 * 64];
  __shared__ bf16 Bs[2 * 128 * 64];
  gemm_core(As, Bs,
            XsN + (size_t)blockIdx.y * 128 * 512,
            Wt + (size_t)blockIdx.x * 128 * 512,
            qkv, 512, 512, 768, 8, amap, bmap,
            blockIdx.y * 128, blockIdx.x * 128, 2, false, norms);
}

// fused sim + qkv dispatch (big-ws path): grid (928).  qkv tail blocks are
// XCD-affine: tail on XCD x handles A-rows of batch x>>1 (already L2-resident
// from that XCD's sim blocks).
__global__ __launch_bounds__(256) void gemm_fused_kernel(const bf16* __restrict__ XsN,
                                                         float* __restrict__ sim,
                                                         int amap_s, int bmap_s,
                                                         const bf16* __restrict__ Wt,
                                                         bf16* __restrict__ qkv,
                                                         int amap_q, int bmap_q,
                                                         const float* __restrict__ norms) {
  __shared__ bf16 As[2 * 128 * 64];
  __shared__ bf16 Bs[2 * 128 * 64];
  int g = blockIdx.x;
  if (g < 544) {
    int xcd = g & 7;
    int slot = g >> 3;
    int z = xcd >> 1;
    int t = (xcd & 1) * 68 + slot;
    int by = 0;
    while (t >= 16 - by) { t -= 16 - by; ++by; }
    int bx = by + t;
    gemm_core(As, Bs,
              XsN + (size_t)z * N * 512 + (size_t)by * 128 * 512,
              XsN + (size_t)z * N * 512 + (size_t)bx * 128 * 512,
              sim + (size_t)z * N * N,
              512, 512, N, 12, amap_s, bmap_s, by * 128, bx * 128,
              1, bx != by, nullptr);
  } else {
    int t = g - 544;
    int xcd = t & 7;            // same round-robin position as sim blocks
    int slot = t >> 3;          // 0..47
    int by = (xcd >> 1) * 16 + (xcd & 1) * 8 + slot / 6;  // batch-affine rows
    int bx = slot % 6;
    gemm_core(As, Bs,
              XsN + (size_t)by * 128 * 512,
              Wt + (size_t)bx * 128 * 512,
              qkv, 512, 512, 768, 8, amap_q, bmap_q,
              by * 128, bx * 128, 2, false, norms);
  }
}

// ---------------------------------------------------------------------------
// top-9 per row by 9x extract-max, fused adjacency write.  One wave per row;
// mask pre-zeroed.  Selection set identical to lax.top_k.
// ---------------------------------------------------------------------------
__global__ __launch_bounds__(64) void topk_adj_kernel(const float* __restrict__ sim,
                                                      unsigned* __restrict__ mask) {
  int row = blockIdx.x;
  int lane = threadIdx.x;
  int b = row >> 11, r = row & 2047;
  const float* srow = sim + (size_t)row * N;
  float v[32];
#pragma unroll
  for (int it = 0; it < 8; ++it) {
    float4 q = *(const float4*)(srow + it * 256 + lane * 4);
    v[it * 4 + 0] = q.x; v[it * 4 + 1] = q.y;
    v[it * 4 + 2] = q.z; v[it * 4 + 3] = q.w;
  }
  unsigned removed = 0;
  for (int rs = 0; rs < TOPK; ++rs) {
    float m = -3e38f;
    int mi = 0;
#pragma unroll
    for (int i = 0; i < 32; ++i) {
      float vv = ((removed >> i) & 1u) ? -3e38f : v[i];
      if (vv > m) { m = vv; mi = i; }
    }
    int gidx = ((mi >> 2) << 8) + lane * 4 + (mi & 3);
    for (int off = 32; off; off >>= 1) {
      float om = __shfl_down(m, off);
      int og = __shfl_down(gidx, off);
      if (om > m || (om == m && og < gidx)) { m = om; gidx = og; }
    }
    gidx = __shfl(gidx, 0);
    if (((gidx >> 2) & 63) == lane)
      removed |= 1u << (((gidx >> 8) << 2) | (gidx & 3));
    if (lane == 0) {
      atomicOr(&mask[(size_t)row * 64 + (gidx >> 5)], 1u << (gidx & 31));
      atomicOr(&mask[(((size_t)b << 11) + gidx) * 64 + (r >> 5)], 1u << (r & 31));
    }
  }
}

// ---------------------------------------------------------------------------
// sparse attention: 4 waves/block, one (b,n) row per wave; XCD-aware decode;
// qkv is bf16 [8192][768]; writes bf16-split aos (stride 512).
// ---------------------------------------------------------------------------
__global__ __launch_bounds__(256) void attn_kernel(const bf16* __restrict__ qkv,
                                                   const unsigned* __restrict__ mask,
                                                   bf16* __restrict__ aos) {
  __shared__ float sq[4][256];
  __shared__ unsigned short nbr[4][2048];
  __shared__ int s_nn[4];
  int wv = threadIdx.x >> 6;
  int lane = threadIdx.x & 63;
  int g = blockIdx.x;
  int xcd = g & 7;
  int b = xcd >> 1;
  int tile = (xcd & 1) * 256 + (g >> 3);
  int bn = b * N + tile * 4 + wv;
  if (lane == 0) s_nn[wv] = 0;
  {
    bf16x4 qv = *(const bf16x4*)(qkv + (size_t)bn * 768 + lane * 4);
#pragma unroll
    for (int j = 0; j < 4; ++j) sq[wv][lane * 4 + j] = (float)qv[j];
  }
  __syncthreads();
  unsigned bits = mask[(size_t)bn * (N / 32) + lane];
  while (bits) {
    int bit = __ffs(bits) - 1;
    bits &= bits - 1;
    int p = atomicAdd(&s_nn[wv], 1);
    nbr[wv][p] = (unsigned short)(lane * 32 + bit);
  }
  __syncthreads();
  int nn = s_nn[wv];
  const bf16* base = qkv + (size_t)b * N * 768;
  float acc[4] = {0.f, 0.f, 0.f, 0.f};

  auto score4 = [&](int j, float* s) {
    const bf16* kr = base + (size_t)j * 768 + 256;
#pragma unroll
    for (int h = 0; h < 4; ++h) {
      float a = 0.f;
#pragma unroll
      for (int c = 0; c < DH; c += 8) {
        bf16x8 kk = *(const bf16x8*)(kr + h * DH + c);
#pragma unroll
        for (int t = 0; t < 8; ++t) a += sq[wv][h * DH + c + t] * (float)kk[t];
      }
      s[h] = a * 0.125f;
    }
  };

  if (nn <= 64) {
    float s[4] = {NEG_BIG, NEG_BIG, NEG_BIG, NEG_BIG};
    if (lane < nn) score4(nbr[wv][lane], s);
    float w[4], l[4];
#pragma unroll
    for (int h = 0; h < 4; ++h) {
      float m = s[h];
      for (int off = 32; off; off >>= 1) m = fmaxf(m, __shfl_down(m, off));
      m = __shfl(m, 0);
      float e = (lane < nn) ? __expf(s[h] - m) : 0.f;
      float ls = e;
      for (int off = 32; off; off >>= 1) ls += __shfl_down(ls, off);
      l[h] = __shfl(ls, 0);
      w[h] = e;
    }
    int i = 0;
    for (; i + 4 <= nn; i += 4) {
      int j0 = nbr[wv][i + 0], j1 = nbr[wv][i + 1];
      int j2 = nbr[wv][i + 2], j3 = nbr[wv][i + 3];
      const bf16* p0 = base + (size_t)j0 * 768 + 512;
      const bf16* p1 = base + (size_t)j1 * 768 + 512;
      const bf16* p2 = base + (size_t)j2 * 768 + 512;
      const bf16* p3 = base + (size_t)j3 * 768 + 512;
#pragma unroll
      for (int h = 0; h < 4; ++h) {
        acc[h] += __shfl(w[h], i + 0) * (float)p0[h * DH + lane] +
                  __shfl(w[h], i + 1) * (float)p1[h * DH + lane] +
                  __shfl(w[h], i + 2) * (float)p2[h * DH + lane] +
                  __shfl(w[h], i + 3) * (float)p3[h * DH + lane];
      }
    }
    for (; i < nn; ++i) {
      const bf16* p0 = base + (size_t)nbr[wv][i] * 768 + 512;
#pragma unroll
      for (int h = 0; h < 4; ++h) acc[h] += __shfl(w[h], i) * (float)p0[h * DH + lane];
    }
#pragma unroll
    for (int h = 0; h < 4; ++h) acc[h] /= l[h];
  } else {
    float m[4] = {NEG_BIG, NEG_BIG, NEG_BIG, NEG_BIG};
    for (int i0 = 0; i0 < nn; i0 += 64) {
      float s[4] = {NEG_BIG, NEG_BIG, NEG_BIG, NEG_BIG};
      if (i0 + lane < nn) score4(nbr[wv][i0 + lane], s);
#pragma unroll
      for (int h = 0; h < 4; ++h) m[h] = fmaxf(m[h], s[h]);
    }
#pragma unroll
    for (int h = 0; h < 4; ++h) {
      for (int off = 32; off; off >>= 1) m[h] = fmaxf(m[h], __shfl_down(m[h], off));
      m[h] = __shfl(m[h], 0);
    }
    float l[4] = {0.f, 0.f, 0.f, 0.f};
    for (int i0 = 0; i0 < nn; i0 += 64) {
      float s[4] = {NEG_BIG, NEG_BIG, NEG_BIG, NEG_BIG};
      if (i0 + lane < nn) score4(nbr[wv][i0 + lane], s);
      float e[4];
#pragma unroll
      for (int h = 0; h < 4; ++h) {
        e[h] = (i0 + lane < nn) ? __expf(s[h] - m[h]) : 0.f;
        float ls = e[h];
        for (int off = 32; off; off >>= 1) ls += __shfl_down(ls, off);
        l[h] += __shfl(ls, 0);
      }
      int lim = min(64, nn - i0);
      for (int ii = 0; ii < lim; ++ii) {
        const bf16* p0 = base + (size_t)nbr[wv][i0 + ii] * 768 + 512;
#pragma unroll
        for (int h = 0; h < 4; ++h) acc[h] += __shfl(e[h], ii) * (float)p0[h * DH + lane];
      }
    }
#pragma unroll
    for (int h = 0; h < 4; ++h) acc[h] /= l[h];
  }
#pragma unroll
  for (int h = 0; h < 4; ++h) {
    float a = acc[h];
    bf16 hi = (bf16)a;
    aos[(size_t)bn * 512 + h * DH + lane] = hi;
    aos[(size_t)bn * 512 + 256 + h * DH + lane] = (bf16)(a - (float)hi);
  }
}

// ---------------------------------------------------------------------------
// fused out-projection + bias + residual + LayerNorm -> out.
// 32 rows x 256 cols per block (grid 256 — every CU busy), BK=32, LDS dbuf,
// swizzle key (r>>1)&3 (0 conflicts, round 10).  Per-row LN: 16-lane shuffle
// + 4-wave LDS combine.
// ---------------------------------------------------------------------------
__global__ __launch_bounds__(256) void projln_kernel(const bf16* __restrict__ A,
                                                     const bf16* __restrict__ Bw,
                                                     const float* __restrict__ x,
                                                     const float* __restrict__ bo,
                                                     const float* __restrict__ gamma,
                                                     const float* __restrict__ beta,
                                                     float* __restrict__ out) {
  __shared__ bf16 As[2 * 32 * 32];     // 4 KB
  __shared__ bf16 Bs[2 * 256 * 32];    // 32 KB
  __shared__ float rsum[32][4];
  __shared__ float rsq[32][4];
  int tid = threadIdx.x;
  int lane = tid & 63;
  int wv = tid >> 6;
  int wn = wv * 64;                    // each wave: all 32 rows x 64 cols
  int row0 = blockIdx.x * 32;

  int rt = tid >> 2;                   // B row helper 0..63
  int ra = tid >> 2;                   // A row 0..31 (tid<128)
  int gpa = (tid & 3) ^ ((ra >> 1) & 3);
  const bf16* ga0 = A + (size_t)(row0 + ra) * 512 + gpa * 8;

  int fr = lane & 15;
  int G = lane >> 4;

  f32x4 acc[2][4] = {};

  auto issue = [&](int st, int buf) {
    int aoff = ((st >> 3) << 8) | ((st & 7) << 5);  // A: ch0 h, ch1 m
    int boff = (st & 7) << 5;                       // B: h only
    if (tid < 128)
      async_cp16(ga0 + aoff, &As[buf * 1024 + tid * 8]);
#pragma unroll
    for (int q = 0; q < 4; ++q) {
      int rb = q * 64 + rt;
      int gpb = (tid & 3) ^ ((rb >> 1) & 3);
      async_cp16(Bw + (size_t)rb * 512 + gpb * 8 + boff,
                 &Bs[buf * 8192 + (q * 256 + tid) * 8]);
    }
  };

  issue(0, 0);
  for (int st = 0; st < 16; ++st) {
    int buf = st & 1;
    if (st + 1 < 16) {
      issue(st + 1, buf ^ 1);
      WAITVM(4);  // waves 2-3: exactly st retired; waves 0-1: slightly stricter
    } else {
      WAITVM(0);
    }
    __builtin_amdgcn_s_barrier();
    bf16x8 af[2], bfr[4];
#pragma unroll
    for (int mi = 0; mi < 2; ++mi) {
      int r = mi * 16 + fr;
      af[mi] = *(const bf16x8*)&As[buf * 1024 + r * 32 + ((G ^ ((r >> 1) & 3)) << 3)];
    }
#pragma unroll
    for (int nj = 0; nj < 4; ++nj) {
      int r = wn + nj * 16 + fr;
      bfr[nj] = *(const bf16x8*)&Bs[buf * 8192 + r * 32 + ((G ^ ((r >> 1) & 3)) << 3)];
    }
#pragma unroll
    for (int mi = 0; mi < 2; ++mi)
#pragma unroll
      for (int nj = 0; nj < 4; ++nj)
        acc[mi][nj] = __builtin_amdgcn_mfma_f32_16x16x32_bf16(af[mi], bfr[nj], acc[mi][nj], 0, 0, 0);
    __builtin_amdgcn_s_barrier();
  }

  int er = (lane >> 4) * 4;
  int ec = lane & 15;
  float bo_c[4], ga_c[4], be_c[4];
#pragma unroll
  for (int nj = 0; nj < 4; ++nj) {
    int c = wn + nj * 16 + ec;
    bo_c[nj] = bo[c]; ga_c[nj] = gamma[c]; be_c[nj] = beta[c];
  }
#pragma unroll
  for (int mi = 0; mi < 2; ++mi)
#pragma unroll
    for (int reg = 0; reg < 4; ++reg) {
      int rloc = mi * 16 + er + reg;
      const float* xr = x + (size_t)(row0 + rloc) * D;
      float su = 0.f, s2 = 0.f;
#pragma unroll
      for (int nj = 0; nj < 4; ++nj) {
        float u = acc[mi][nj][reg] + bo_c[nj] + xr[wn + nj * 16 + ec];
        su += u; s2 += u * u;
      }
#pragma unroll
      for (int m = 1; m <= 8; m <<= 1) {
        su += __shfl_xor(su, m);
        s2 += __shfl_xor(s2, m);
      }
      if (ec == 0) { rsum[rloc][wv] = su; rsq[rloc][wv] = s2; }
    }
  __syncthreads();
#pragma unroll
  for (int mi = 0; mi < 2; ++mi)
#pragma unroll
    for (int reg = 0; reg < 4; ++reg) {
      int rloc = mi * 16 + er + reg;
      float s = rsum[rloc][0] + rsum[rloc][1] + rsum[rloc][2] + rsum[rloc][3];
      float q2 = rsq[rloc][0] + rsq[rloc][1] + rsq[rloc][2] + rsq[rloc][3];
      float mean = s * (1.0f / D);
      float var = q2 * (1.0f / D) - mean * mean;
      float rstd = rsqrtf(var + 1e-5f);
      const float* xr = x + (size_t)(row0 + rloc) * D;
      float* orow = out + (size_t)(row0 + rloc) * D;
#pragma unroll
      for (int nj = 0; nj < 4; ++nj) {
        float u = acc[mi][nj][reg] + bo_c[nj] + xr[wn + nj * 16 + ec];
        orow[wn + nj * 16 + ec] = (u - mean) * rstd * ga_c[nj] + be_c[nj];
      }
    }
}

// ---------------------------------------------------------------------------
// Workspace.  Common: XsN [0,8.39M) | sim [12.58M,79.69M) | norms@79.69M
//                     mask@79.99M | Wt@82.08M (ends 83,132,416)
// BIG (ws >= 125 MB; fill shows 256 MiB): qkv(bf16)@83.13M | aos@95.72M
// SMALL: qkv@12.58M, aos@37.75M (dead-sim region, written after topk)
// ---------------------------------------------------------------------------
extern "C" void kernel_launch(void* const* d_in, const int* in_sizes, int n_in,
                              void* d_out, int out_size, void* d_ws, size_t ws_size,
                              hipStream_t stream) {
  const float* x     = (const float*)d_in[0];
  const float* Wq    = (const float*)d_in[1];
  const float* Wk    = (const float*)d_in[2];
  const float* Wv    = (const float*)d_in[3];
  const float* Wo    = (const float*)d_in[4];
  const float* bo    = (const float*)d_in[5];
  const float* gamma = (const float*)d_in[6];
  const float* beta  = (const float*)d_in[7];
  float* out = (float*)d_out;

  char* ws = (char*)d_ws;
  bf16* XsN      = (bf16*)(ws);
  float* sim     = (float*)(ws + 12582912);
  float* norms   = (float*)(ws + 79691776);
  unsigned* mask = (unsigned*)(ws + 79986688);
  bf16* Wt       = (bf16*)(ws + 82083840);

  bool big = ws_size >= (size_t)125000000;
  bf16* qkv = (bf16*)(ws + (big ? 83132416 : 12582912));
  bf16* aos = (bf16*)(ws + (big ? 95715328 : 37748736));

  const int AMAP_SIM = PK6(0, 0, 1, 0, 0, 0);  // hh + hm + mh
  const int BMAP_SIM = PK6(0, 1, 0, 0, 0, 0);
  const int AMAP_2T  = PK3(0, 1, 0);           // (h+m)_A · h_B
  const int BMAP_2T  = PK3(0, 0, 1);

  prep_kernel<<<9344, 64, 0, stream>>>(x, Wq, Wk, Wv, Wo, XsN, Wt, norms,
                                       (uint4*)mask);

  if (big) {
    gemm_fused_kernel<<<928, 256, 0, stream>>>(
        XsN, sim, AMAP_SIM, BMAP_SIM, Wt, qkv, AMAP_2T, BMAP_2T, norms);
    topk_adj_kernel<<<BATCH * N, 64, 0, stream>>>(sim, mask);
  } else {
    gemm_sim_kernel<<<544, 256, 0, stream>>>(XsN, sim, AMAP_SIM, BMAP_SIM);
    topk_adj_kernel<<<BATCH * N, 64, 0, stream>>>(sim, mask);
    gemm_qkv_kernel<<<dim3(6, 64), 256, 0, stream>>>(XsN, Wt, qkv,
                                                     AMAP_2T, BMAP_2T, norms);
  }

  attn_kernel<<<(BATCH * N) / 4, 256, 0, stream>>>(qkv, mask, aos);

  projln_kernel<<<256, 256, 0, stream>>>(aos, Wt + (size_t)768 * 512,
                                         x, bo, gamma, beta, out);
}